// Round 3
// baseline (900.566 us; speedup 1.0000x reference)
//
#include <hip/hip_runtime.h>
#include <hip/hip_bf16.h>

// Problem constants
#define BB 8
#define SS 4096
#define DD 1024
#define HH 16
#define LL 6
#define FF 2048
#define VV 256

// ---------------- positional encoding ----------------
__global__ __launch_bounds__(256) void pe_kernel(float* __restrict__ pe) {
    int s = blockIdx.x;
    float fs = (float)s;
    for (int i = threadIdx.x; i < DD / 2; i += 256) {
        float div = expf((-logf(10000.0f) / (float)DD) * (float)(2 * i));
        float a = fs * div;
        pe[(long)s * DD + 2 * i]     = sinf(a);
        pe[(long)s * DD + 2 * i + 1] = cosf(a);
    }
}

// ---------------- generic small GEMM (M=8), one wave per output column ----------------
// K compile-time -> full unroll, weight loads issued up front (latency fix).
template <int K, int RELU>
__global__ __launch_bounds__(256) void gemm8(
    const float* __restrict__ A, long sA,
    const float* __restrict__ A2, long sA2,
    const float* __restrict__ W,
    const float* __restrict__ bias,
    const float* __restrict__ R1, long sR1,
    const float* __restrict__ R2, long sR2,
    float* __restrict__ C, int N)
{
    int wave = threadIdx.x >> 6, lane = threadIdx.x & 63;
    int n = blockIdx.x * 4 + wave;
    if (n >= N) return;
    float acc[8] = {0.f,0.f,0.f,0.f,0.f,0.f,0.f,0.f};
    const float4* W4 = reinterpret_cast<const float4*>(W + (long)n * K);
    // hoist all weight loads (independent addresses)
    float4 wv[K / 256];
    #pragma unroll
    for (int kb = 0; kb < K / 256; ++kb) wv[kb] = W4[kb * 64 + lane];
    #pragma unroll
    for (int kb = 0; kb < K / 256; ++kb) {
        int k4 = kb * 64 + lane;
        float4 w = wv[kb];
        #pragma unroll
        for (int m = 0; m < 8; ++m) {
            float4 a = reinterpret_cast<const float4*>(A + (long)m * sA)[k4];
            if (A2) {
                float4 a2 = reinterpret_cast<const float4*>(A2 + (long)m * sA2)[k4];
                a.x += a2.x; a.y += a2.y; a.z += a2.z; a.w += a2.w;
            }
            acc[m] += a.x * w.x + a.y * w.y + a.z * w.z + a.w * w.w;
        }
    }
    #pragma unroll
    for (int m = 0; m < 8; ++m)
        for (int off = 32; off; off >>= 1) acc[m] += __shfl_xor(acc[m], off, 64);
    if (lane == 0) {
        float bs = bias ? bias[n] : 0.f;
        #pragma unroll
        for (int m = 0; m < 8; ++m) {
            float v = acc[m] + bs;
            if (R1) v += R1[(long)m * sR1 + n];
            if (R2) v += R2[(long)m * sR2 + n];
            if (RELU) v = fmaxf(v, 0.f);
            C[(long)m * N + n] = v;
        }
    }
}

// ---------------- LayerNorm over last dim for 8 rows ----------------
__global__ __launch_bounds__(256) void ln8(const float* __restrict__ x,
                                           const float* __restrict__ w,
                                           const float* __restrict__ b,
                                           float* __restrict__ o, int N)
{
    int m = blockIdx.x, t = threadIdx.x;
    const float* xr = x + (long)m * N;
    float s1 = 0.f, s2 = 0.f;
    for (int k = t; k < N; k += 256) { float v = xr[k]; s1 += v; s2 += v * v; }
    __shared__ float r1[4], r2[4];
    for (int off = 32; off; off >>= 1) { s1 += __shfl_xor(s1, off, 64); s2 += __shfl_xor(s2, off, 64); }
    if ((t & 63) == 0) { r1[t >> 6] = s1; r2[t >> 6] = s2; }
    __syncthreads();
    s1 = r1[0] + r1[1] + r1[2] + r1[3];
    s2 = r2[0] + r2[1] + r2[2] + r2[3];
    float mean = s1 / (float)N;
    float var  = s2 / (float)N - mean * mean;
    float rstd = rsqrtf(var + 1e-5f);
    for (int k = t; k < N; k += 256)
        o[(long)m * N + k] = (xr[k] - mean) * rstd * w[k] + b[k];
}

// ---------------- u[b,h,:] = sum_d Q[b, h*64+d] * wk[h*64+d, :] ----------------
__global__ __launch_bounds__(256) void u_kernel(const float* __restrict__ Q,
                                                const float* __restrict__ wk,
                                                float* __restrict__ u)
{
    int h = blockIdx.y;
    int e = blockIdx.x * 256 + threadIdx.x;
    __shared__ float qs[8][64];
    for (int idx = threadIdx.x; idx < 512; idx += 256) {
        int b = idx >> 6, d = idx & 63;
        qs[b][d] = Q[(long)b * DD + h * 64 + d];
    }
    __syncthreads();
    float acc[8] = {0.f,0.f,0.f,0.f,0.f,0.f,0.f,0.f};
    for (int d = 0; d < 64; ++d) {
        float wv = wk[(long)(h * 64 + d) * DD + e];
        #pragma unroll
        for (int b = 0; b < 8; ++b) acc[b] += qs[b][d] * wv;
    }
    #pragma unroll
    for (int b = 0; b < 8; ++b) u[((long)(b * HH + h)) * DD + e] = acc[b];
}

// ---------------- fused flash-decode attention ----------------
// grid (NCH, BB). Block owns (b, s-chunk of SS/NCH). tgt read from HBM once.
// Per 16-s sub-chunk: score phase -> online-softmax update -> ctx accumulate.
template <int NCH>
__global__ __launch_bounds__(256) void flash_kernel(const float* __restrict__ tgt,
                                                    const float* __restrict__ pe,
                                                    const float* __restrict__ u,
                                                    float* __restrict__ part,
                                                    float* __restrict__ mstat,
                                                    float* __restrict__ lstat)
{
    constexpr int CHS = SS / NCH;   // s per chunk
    constexpr int NSUB = CHS / 16;
    int c = blockIdx.x, b = blockIdx.y;
    int t = threadIdx.x;
    __shared__ float us[16 * 1024];                  // 64 KB u-tile
    __shared__ __align__(16) float pbuf[16][16];     // scores then probs, [h][s_local]
    __shared__ float mh[16], lh[16], rh[16];

    {   // stage u[b] into LDS
        const float4* ub4 = reinterpret_cast<const float4*>(u + (long)b * HH * DD);
        float4* us4w = reinterpret_cast<float4*>(us);
        for (int i = t; i < 16 * 1024 / 4; i += 256) us4w[i] = ub4[i];
    }
    if (t < 16) { mh[t] = -3.0e38f; lh[t] = 0.f; }
    float acc[16][4];
    #pragma unroll
    for (int h = 0; h < 16; ++h) { acc[h][0] = acc[h][1] = acc[h][2] = acc[h][3] = 0.f; }
    __syncthreads();

    int wave = t >> 6, lane = t & 63;
    int s_base = c * CHS;
    const float4* us4 = reinterpret_cast<const float4*>(us);

    for (int sub = 0; sub < NSUB; ++sub) {
        int s0 = s_base + sub * 16;
        // ---- score phase: wave handles s_local in [wave*4, wave*4+4), 2 pairs ----
        #pragma unroll
        for (int pr = 0; pr < 2; ++pr) {
            int sl = wave * 4 + pr * 2;
            int s = s0 + sl;
            float sacc[16][2];
            #pragma unroll
            for (int h = 0; h < 16; ++h) { sacc[h][0] = 0.f; sacc[h][1] = 0.f; }
            const float4* x0p = reinterpret_cast<const float4*>(tgt + ((long)b * SS + s) * DD);
            const float4* x1p = reinterpret_cast<const float4*>(tgt + ((long)b * SS + s + 1) * DD);
            const float4* p0p = reinterpret_cast<const float4*>(pe + (long)s * DD);
            const float4* p1p = reinterpret_cast<const float4*>(pe + (long)(s + 1) * DD);
            #pragma unroll
            for (int kb = 0; kb < 4; ++kb) {
                int j = kb * 64 + lane;
                float4 a0 = x0p[j], q0 = p0p[j];
                float4 xv0 = make_float4(a0.x + q0.x, a0.y + q0.y, a0.z + q0.z, a0.w + q0.w);
                float4 a1 = x1p[j], q1 = p1p[j];
                float4 xv1 = make_float4(a1.x + q1.x, a1.y + q1.y, a1.z + q1.z, a1.w + q1.w);
                #pragma unroll
                for (int h = 0; h < 16; ++h) {
                    float4 uv = us4[h * 256 + j];
                    sacc[h][0] += uv.x * xv0.x + uv.y * xv0.y + uv.z * xv0.z + uv.w * xv0.w;
                    sacc[h][1] += uv.x * xv1.x + uv.y * xv1.y + uv.z * xv1.z + uv.w * xv1.w;
                }
            }
            #pragma unroll
            for (int h = 0; h < 16; ++h)
                #pragma unroll
                for (int r2 = 0; r2 < 2; ++r2) {
                    float v = sacc[h][r2];
                    for (int off = 32; off; off >>= 1) v += __shfl_xor(v, off, 64);
                    if (lane == 0) pbuf[h][sl + r2] = v * 0.125f;
                }
        }
        __syncthreads();
        // ---- online-softmax update: thread (h = t>>4, sj = t&15) ----
        {
            int h = t >> 4, sj = t & 15;
            float sv = pbuf[h][sj];
            float mloc = sv;
            #pragma unroll
            for (int off = 8; off; off >>= 1) mloc = fmaxf(mloc, __shfl_xor(mloc, off, 16));
            float mold = mh[h];
            float mnew = fmaxf(mold, mloc);
            float pj = expf(sv - mnew);
            float lsum = pj;
            #pragma unroll
            for (int off = 8; off; off >>= 1) lsum += __shfl_xor(lsum, off, 16);
            pbuf[h][sj] = pj;
            if (sj == 0) {
                float r = expf(mold - mnew);   // 0 on first sub-chunk
                mh[h] = mnew;
                lh[h] = lh[h] * r + lsum;
                rh[h] = r;
            }
        }
        __syncthreads();
        // ---- ctx phase: thread owns e-strip of 4, full D covered by 256 threads ----
        {
            int e = t * 4;
            #pragma unroll
            for (int h = 0; h < 16; ++h) {
                float r = rh[h];
                acc[h][0] *= r; acc[h][1] *= r; acc[h][2] *= r; acc[h][3] *= r;
            }
            #pragma unroll
            for (int sg = 0; sg < 4; ++sg) {
                float4 x[4];
                #pragma unroll
                for (int r2 = 0; r2 < 4; ++r2) {
                    int s = s0 + sg * 4 + r2;
                    float4 tv = *reinterpret_cast<const float4*>(tgt + ((long)b * SS + s) * DD + e);
                    float4 pv = *reinterpret_cast<const float4*>(pe + (long)s * DD + e);
                    x[r2] = make_float4(tv.x + pv.x, tv.y + pv.y, tv.z + pv.z, tv.w + pv.w);
                }
                #pragma unroll
                for (int h = 0; h < 16; ++h) {
                    float4 pw = *reinterpret_cast<const float4*>(&pbuf[h][sg * 4]);
                    acc[h][0] += pw.x * x[0].x + pw.y * x[1].x + pw.z * x[2].x + pw.w * x[3].x;
                    acc[h][1] += pw.x * x[0].y + pw.y * x[1].y + pw.z * x[2].y + pw.w * x[3].y;
                    acc[h][2] += pw.x * x[0].z + pw.y * x[1].z + pw.z * x[2].z + pw.w * x[3].z;
                    acc[h][3] += pw.x * x[0].w + pw.y * x[1].w + pw.z * x[2].w + pw.w * x[3].w;
                }
            }
        }
        __syncthreads();
    }
    // ---- write per-chunk partials + stats ----
    {
        int e = t * 4;
        #pragma unroll
        for (int h = 0; h < 16; ++h) {
            float4 v = make_float4(acc[h][0], acc[h][1], acc[h][2], acc[h][3]);
            *reinterpret_cast<float4*>(part + (((long)c * BB + b) * HH + h) * DD + e) = v;
        }
        if (t < 16) {
            mstat[((long)(b * HH + t)) * NCH + c] = mh[t];
            lstat[((long)(b * HH + t)) * NCH + c] = lh[t];
        }
    }
}

// ---------------- combine chunk partials -> ctx[b,h,e] ----------------
template <int NCH>
__global__ __launch_bounds__(256) void flashred_kernel(const float* __restrict__ part,
                                                       const float* __restrict__ mstat,
                                                       const float* __restrict__ lstat,
                                                       float* __restrict__ ctx)
{
    int bh = blockIdx.x;   // b*HH + h
    int b = bh >> 4, h = bh & 15;
    __shared__ float wbuf[NCH > 64 ? NCH : 64];
    __shared__ float sinvL;
    int t = threadIdx.x;
    if (t < 64) {
        float m = (t < NCH) ? mstat[(long)bh * NCH + t] : -3.0e38f;
        float l = (t < NCH) ? lstat[(long)bh * NCH + t] : 0.f;
        float M = m;
        for (int off = 32; off; off >>= 1) M = fmaxf(M, __shfl_xor(M, off, 64));
        float w = expf(m - M);
        float Lc = w * l;
        float L = Lc;
        for (int off = 32; off; off >>= 1) L += __shfl_xor(L, off, 64);
        if (t < NCH) wbuf[t] = w;
        if (t == 0) sinvL = 1.f / L;
    }
    __syncthreads();
    int e = t * 4;
    float4 a = make_float4(0.f, 0.f, 0.f, 0.f);
    for (int c = 0; c < NCH; ++c) {
        float w = wbuf[c];
        float4 p = *reinterpret_cast<const float4*>(part + (((long)c * BB + b) * HH + h) * DD + e);
        a.x += w * p.x; a.y += w * p.y; a.z += w * p.z; a.w += w * p.w;
    }
    float invL = sinvL;
    *reinterpret_cast<float4*>(ctx + (long)bh * DD + e) =
        make_float4(a.x * invL, a.y * invL, a.z * invL, a.w * invL);
}

// ---------------- o[b, j] = sum_e wv[j,e]*ctx[b, j>>6, e] + bv[j] ----------------
__global__ __launch_bounds__(256) void ov_kernel(const float* __restrict__ ctx,
                                                 const float* __restrict__ wv,
                                                 const float* __restrict__ bv,
                                                 float* __restrict__ o)
{
    int wave = threadIdx.x >> 6, lane = threadIdx.x & 63;
    int j = blockIdx.x * 4 + wave;
    if (j >= DD) return;
    int h = j >> 6;
    float acc[8] = {0.f,0.f,0.f,0.f,0.f,0.f,0.f,0.f};
    const float4* w4 = reinterpret_cast<const float4*>(wv + (long)j * DD);
    float4 wreg[4];
    #pragma unroll
    for (int kb = 0; kb < 4; ++kb) wreg[kb] = w4[kb * 64 + lane];
    #pragma unroll
    for (int kb = 0; kb < 4; ++kb) {
        int k4 = kb * 64 + lane;
        float4 w = wreg[kb];
        #pragma unroll
        for (int b = 0; b < 8; ++b) {
            float4 a = reinterpret_cast<const float4*>(ctx + ((long)(b * HH + h)) * DD)[k4];
            acc[b] += a.x * w.x + a.y * w.y + a.z * w.z + a.w * w.w;
        }
    }
    #pragma unroll
    for (int b = 0; b < 8; ++b)
        for (int off = 32; off; off >>= 1) acc[b] += __shfl_xor(acc[b], off, 64);
    if (lane == 0) {
        float bs = bv[j];
        #pragma unroll
        for (int b = 0; b < 8; ++b) o[(long)b * DD + j] = acc[b] + bs;
    }
}

// -------- attention driver for a given NCH (ws-size dependent) --------
template <int NCH>
static void run_attn(const float* tgt, const float* pe, const float* u,
                     float* part, float* mstat, float* lstat, float* ctx,
                     hipStream_t stream)
{
    flash_kernel<NCH><<<dim3(NCH, BB), 256, 0, stream>>>(tgt, pe, u, part, mstat, lstat);
    flashred_kernel<NCH><<<BB * HH, 256, 0, stream>>>(part, mstat, lstat, ctx);
}

extern "C" void kernel_launch(void* const* d_in, const int* in_sizes, int n_in,
                              void* d_out, int out_size, void* d_ws, size_t ws_size,
                              hipStream_t stream)
{
    const float* tgt        = (const float*)d_in[0];
    const float* in_proj_w  = (const float*)d_in[1];
    const float* in_proj_b  = (const float*)d_in[2];
    const float* out_proj_w = (const float*)d_in[3];
    const float* out_proj_b = (const float*)d_in[4];
    const float* ln1_w      = (const float*)d_in[5];
    const float* ln1_b      = (const float*)d_in[6];
    const float* lin1_w     = (const float*)d_in[7];
    const float* lin1_b     = (const float*)d_in[8];
    const float* lin2_w     = (const float*)d_in[9];
    const float* lin2_b     = (const float*)d_in[10];
    const float* ln2_w      = (const float*)d_in[11];
    const float* ln2_b      = (const float*)d_in[12];
    const float* w_out      = (const float*)d_in[13];
    const float* b_out      = (const float*)d_in[14];

    // pick NCH by workspace size (constant across calls -> same work every call)
    int nch = 64;
    {
        auto need = [](long n) {
            long f = (long)SS * DD + (long)BB * HH * DD   // pe + u
                   + n * BB * HH * DD                      // part
                   + 2L * BB * HH * n                      // mstat/lstat
                   + (long)BB * HH * DD                    // ctx
                   + 6L * BB * DD + (long)BB * FF + (long)BB * DD + 1024; // small bufs + pad
            return f * (long)sizeof(float);
        };
        if ((long)ws_size < need(64)) nch = 32;
        if ((long)ws_size < need(32)) nch = 16;
    }

    float* ws    = (float*)d_ws;
    float* pe    = ws;                         long off = (long)SS * DD;
    float* u     = ws + off;                   off += (long)BB * HH * DD;
    float* part  = ws + off;                   off += (long)nch * BB * HH * DD;
    float* mstat = ws + off;                   off += (long)BB * HH * nch;
    float* lstat = ws + off;                   off += (long)BB * HH * nch;
    float* ctx   = ws + off;                   off += (long)BB * HH * DD;
    float* Q     = ws + off;                   off += (long)BB * DD;
    float* o     = ws + off;                   off += (long)BB * DD;
    float* x0    = ws + off;                   off += (long)BB * DD;
    float* vb    = ws + off;                   off += (long)BB * DD;
    float* o2    = ws + off;                   off += (long)BB * DD;
    float* y     = ws + off;                   off += (long)BB * DD;
    float* hb    = ws + off;                   off += (long)BB * FF;
    float* z     = ws + off;

    const float* tgt_last = tgt + (long)(SS - 1) * DD;
    const float* pe_last  = pe + (long)(SS - 1) * DD;

    // 1. positional encoding table
    pe_kernel<<<SS, 256, 0, stream>>>(pe);

    // 2. Q = (tgt_last + pe_last) @ wq0^T + bq0
    gemm8<1024, 0><<<DD / 4, 256, 0, stream>>>(tgt_last, (long)SS * DD, pe_last, 0L,
                                               in_proj_w, in_proj_b,
                                               nullptr, 0L, nullptr, 0L, Q, DD);

    // 3. u[b,h,:] = sum_d Q[b,h,d] * wk0[h*64+d,:]   (bk dropped: softmax-invariant)
    u_kernel<<<dim3(4, 16), 256, 0, stream>>>(Q, in_proj_w + (long)DD * DD, u);

    // 4. fused flash attention (tgt read once) + combine
    if (nch == 64)      run_attn<64>(tgt, pe, u, part, mstat, lstat, ctx, stream);
    else if (nch == 32) run_attn<32>(tgt, pe, u, part, mstat, lstat, ctx, stream);
    else                run_attn<16>(tgt, pe, u, part, mstat, lstat, ctx, stream);

    // 5. o[b,:] = wv0 @ ctx + bv0   (sum a = 1 passes bias through)
    ov_kernel<<<DD / 4, 256, 0, stream>>>(ctx, in_proj_w + 2L * DD * DD, in_proj_b + 2 * DD, o);

    // 6. layer-0 tail
    gemm8<1024, 0><<<DD / 4, 256, 0, stream>>>(o, (long)DD, nullptr, 0L,
                                               out_proj_w, out_proj_b,
                                               tgt_last, (long)SS * DD, pe_last, 0L, o2, DD);
    ln8<<<BB, 256, 0, stream>>>(o2, ln1_w, ln1_b, y, DD);
    gemm8<1024, 1><<<FF / 4, 256, 0, stream>>>(y, (long)DD, nullptr, 0L,
                                               lin1_w, lin1_b,
                                               nullptr, 0L, nullptr, 0L, hb, FF);
    gemm8<2048, 0><<<DD / 4, 256, 0, stream>>>(hb, (long)FF, nullptr, 0L,
                                               lin2_w, lin2_b,
                                               y, (long)DD, nullptr, 0L, z, DD);
    ln8<<<BB, 256, 0, stream>>>(z, ln2_w, ln2_b, x0, DD);

    // 7. layers 1..5: seq len 1 -> softmax(1)=1 -> attn out = x @ wv^T + bv
    for (int i = 1; i < LL; ++i) {
        const float* wv_i = in_proj_w + (long)i * 3 * DD * DD + 2L * DD * DD;
        const float* bv_i = in_proj_b + (long)i * 3 * DD + 2 * DD;
        gemm8<1024, 0><<<DD / 4, 256, 0, stream>>>(x0, (long)DD, nullptr, 0L,
                                                   wv_i, bv_i, nullptr, 0L, nullptr, 0L, vb, DD);
        gemm8<1024, 0><<<DD / 4, 256, 0, stream>>>(vb, (long)DD, nullptr, 0L,
                                                   out_proj_w + (long)i * DD * DD,
                                                   out_proj_b + (long)i * DD,
                                                   x0, (long)DD, nullptr, 0L, o2, DD);
        ln8<<<BB, 256, 0, stream>>>(o2, ln1_w + (long)i * DD, ln1_b + (long)i * DD, y, DD);
        gemm8<1024, 1><<<FF / 4, 256, 0, stream>>>(y, (long)DD, nullptr, 0L,
                                                   lin1_w + (long)i * FF * DD, lin1_b + (long)i * FF,
                                                   nullptr, 0L, nullptr, 0L, hb, FF);
        gemm8<2048, 0><<<DD / 4, 256, 0, stream>>>(hb, (long)FF, nullptr, 0L,
                                                   lin2_w + (long)i * DD * FF, lin2_b + (long)i * DD,
                                                   y, (long)DD, nullptr, 0L, z, DD);
        ln8<<<BB, 256, 0, stream>>>(z, ln2_w + (long)i * DD, ln2_b + (long)i * DD, x0, DD);
    }

    // 8. final projection -> (B, 256)
    gemm8<1024, 0><<<VV / 4, 256, 0, stream>>>(x0, (long)DD, nullptr, 0L,
                                               w_out, b_out,
                                               nullptr, 0L, nullptr, 0L, (float*)d_out, VV);
}

// Round 4
// 623.008 us; speedup vs baseline: 1.4455x; 1.4455x over previous
//
#include <hip/hip_runtime.h>
#include <hip/hip_bf16.h>

// Problem constants
#define BB 8
#define SS 4096
#define DD 1024
#define HH 16
#define LL 6
#define FF 2048
#define VV 256
#define NCS 8     // ctx s-chunks

typedef __attribute__((ext_vector_type(8))) short bf16x8;
typedef __attribute__((ext_vector_type(4))) float f32x4;

__device__ __forceinline__ unsigned short f2bf(float f) {
    union { float f; unsigned u; } v; v.f = f;
    unsigned r = v.u + 0x7FFFu + ((v.u >> 16) & 1u);
    return (unsigned short)(r >> 16);
}

// ---------------- positional encoding ----------------
__global__ __launch_bounds__(256) void pe_kernel(float* __restrict__ pe) {
    int s = blockIdx.x;
    float fs = (float)s;
    for (int i = threadIdx.x; i < DD / 2; i += 256) {
        float div = expf((-logf(10000.0f) / (float)DD) * (float)(2 * i));
        float a = fs * div;
        pe[(long)s * DD + 2 * i]     = sinf(a);
        pe[(long)s * DD + 2 * i + 1] = cosf(a);
    }
}

// ---------------- small GEMM (M=8), one wave per output column ----------------
// MODE 0: plain (optional A2 add, optional R1/R2 residuals)
// MODE 1: A rows LayerNorm'd on the fly (lnw/lnb over K)
// MODE 2: epilogue adds ln(lnsrc)[m][n] (lnsrc is 8 x 1024)
template <int K, int RELU, int MODE>
__global__ __launch_bounds__(256) void gemm8k(
    const float* __restrict__ A, long sA,
    const float* __restrict__ A2, long sA2,
    const float* __restrict__ W,
    const float* __restrict__ bias,
    const float* __restrict__ R1, long sR1,
    const float* __restrict__ R2, long sR2,
    const float* __restrict__ lnw, const float* __restrict__ lnb,
    const float* __restrict__ lnsrc,
    float* __restrict__ C, int N)
{
    int wave = threadIdx.x >> 6, lane = threadIdx.x & 63;
    int n = blockIdx.x * 4 + wave;
    if (n >= N) return;

    float mean[8], rstd[8];
    if (MODE != 0) {
        const float* S = (MODE == 1) ? A : lnsrc;
        long ss = (MODE == 1) ? sA : 1024L;
        const int SK = (MODE == 1) ? K : 1024;
        #pragma unroll
        for (int m = 0; m < 8; ++m) {
            float s1 = 0.f, s2 = 0.f;
            const float4* Sr = reinterpret_cast<const float4*>(S + (long)m * ss);
            #pragma unroll
            for (int k4 = 0; k4 < SK / 256; ++k4) {
                float4 a = Sr[k4 * 64 + lane];
                s1 += a.x + a.y + a.z + a.w;
                s2 += a.x * a.x + a.y * a.y + a.z * a.z + a.w * a.w;
            }
            for (int off = 32; off; off >>= 1) {
                s1 += __shfl_xor(s1, off, 64);
                s2 += __shfl_xor(s2, off, 64);
            }
            float mu = s1 / (float)SK;
            mean[m] = mu;
            rstd[m] = rsqrtf(s2 / (float)SK - mu * mu + 1e-5f);
        }
    }

    float acc[8] = {0.f,0.f,0.f,0.f,0.f,0.f,0.f,0.f};
    const float4* W4 = reinterpret_cast<const float4*>(W + (long)n * K);
    float4 wv[K / 256];
    #pragma unroll
    for (int kb = 0; kb < K / 256; ++kb) wv[kb] = W4[kb * 64 + lane];
    #pragma unroll
    for (int kb = 0; kb < K / 256; ++kb) {
        int k4 = kb * 64 + lane;
        float4 w = wv[kb];
        float4 lw, lb;
        if (MODE == 1) {
            lw = reinterpret_cast<const float4*>(lnw)[k4];
            lb = reinterpret_cast<const float4*>(lnb)[k4];
        }
        #pragma unroll
        for (int m = 0; m < 8; ++m) {
            float4 a = reinterpret_cast<const float4*>(A + (long)m * sA)[k4];
            if (A2) {
                float4 a2 = reinterpret_cast<const float4*>(A2 + (long)m * sA2)[k4];
                a.x += a2.x; a.y += a2.y; a.z += a2.z; a.w += a2.w;
            }
            if (MODE == 1) {
                float mu = mean[m], rs = rstd[m];
                a.x = (a.x - mu) * rs * lw.x + lb.x;
                a.y = (a.y - mu) * rs * lw.y + lb.y;
                a.z = (a.z - mu) * rs * lw.z + lb.z;
                a.w = (a.w - mu) * rs * lw.w + lb.w;
            }
            acc[m] += a.x * w.x + a.y * w.y + a.z * w.z + a.w * w.w;
        }
    }
    #pragma unroll
    for (int m = 0; m < 8; ++m)
        for (int off = 32; off; off >>= 1) acc[m] += __shfl_xor(acc[m], off, 64);
    if (lane == 0) {
        float bs = bias ? bias[n] : 0.f;
        #pragma unroll
        for (int m = 0; m < 8; ++m) {
            float v = acc[m] + bs;
            if (MODE == 0) {
                if (R1) v += R1[(long)m * sR1 + n];
                if (R2) v += R2[(long)m * sR2 + n];
            }
            if (MODE == 2)
                v += (lnsrc[(long)m * 1024 + n] - mean[m]) * rstd[m] * lnw[n] + lnb[n];
            if (RELU) v = fmaxf(v, 0.f);
            C[(long)m * N + n] = v;
        }
    }
}

// ---------------- u[b,h,:] = sum_d Q[b, h*64+d] * wk[h*64+d, :]  (bf16 out) ----------------
__global__ __launch_bounds__(256) void u_kernel(const float* __restrict__ Q,
                                                const float* __restrict__ wk,
                                                unsigned short* __restrict__ ub)
{
    int h = blockIdx.y;
    int e = blockIdx.x * 256 + threadIdx.x;
    __shared__ float qs[8][64];
    for (int idx = threadIdx.x; idx < 512; idx += 256) {
        int b = idx >> 6, d = idx & 63;
        qs[b][d] = Q[(long)b * DD + h * 64 + d];
    }
    __syncthreads();
    float acc[8] = {0.f,0.f,0.f,0.f,0.f,0.f,0.f,0.f};
    for (int d = 0; d < 64; ++d) {
        float wv = wk[(long)(h * 64 + d) * DD + e];
        #pragma unroll
        for (int b = 0; b < 8; ++b) acc[b] += qs[b][d] * wv;
    }
    #pragma unroll
    for (int b = 0; b < 8; ++b)
        ub[((long)(b * HH + h)) * DD + e] = f2bf(acc[b]);
}

// ---------------- score: scp[eh][b][h][s] = sum_{e in half} u[b,h,e]*x[b,s,e]  (MFMA) ----------------
// grid (SS/64, 2, BB), block 256 = 4 waves, wave owns 16 s. No LDS, no barriers.
__global__ __launch_bounds__(256) void score_kernel(const float* __restrict__ tgt,
                                                    const float* __restrict__ pe,
                                                    const unsigned short* __restrict__ ub,
                                                    float* __restrict__ scp)
{
    int b = blockIdx.z, h2 = blockIdx.y;
    int wave = threadIdx.x >> 6, lane = threadIdx.x & 63;
    int q = lane >> 4, n = lane & 15;
    int s = blockIdx.x * 64 + wave * 16 + n;
    f32x4 acc = {0.f, 0.f, 0.f, 0.f};
    const float* xrow = tgt + ((long)b * SS + s) * DD;
    const float* prow = pe + (long)s * DD;
    const unsigned short* urow = ub + ((long)(b * HH) + n) * DD;
    #pragma unroll 4
    for (int ks = 0; ks < 16; ++ks) {
        int e0 = h2 * 512 + ks * 32 + q * 8;
        bf16x8 a = *reinterpret_cast<const bf16x8*>(urow + e0);   // A[m=h=lane&15][k=e]
        float4 x0 = *reinterpret_cast<const float4*>(xrow + e0);
        float4 x1 = *reinterpret_cast<const float4*>(xrow + e0 + 4);
        float4 p0 = *reinterpret_cast<const float4*>(prow + e0);
        float4 p1 = *reinterpret_cast<const float4*>(prow + e0 + 4);
        union { short sh[8]; bf16x8 v; } bu;
        bu.sh[0] = (short)f2bf(x0.x + p0.x);
        bu.sh[1] = (short)f2bf(x0.y + p0.y);
        bu.sh[2] = (short)f2bf(x0.z + p0.z);
        bu.sh[3] = (short)f2bf(x0.w + p0.w);
        bu.sh[4] = (short)f2bf(x1.x + p1.x);
        bu.sh[5] = (short)f2bf(x1.y + p1.y);
        bu.sh[6] = (short)f2bf(x1.z + p1.z);
        bu.sh[7] = (short)f2bf(x1.w + p1.w);
        acc = __builtin_amdgcn_mfma_f32_16x16x32_bf16(a, bu.v, acc, 0, 0, 0);
    }
    // C: col = s (lane&15), row = h = q*4 + r
    #pragma unroll
    for (int r = 0; r < 4; ++r) {
        int h = q * 4 + r;
        scp[(((long)h2 * BB + b) * HH + h) * SS + s] = acc[r];
    }
}

// ---------------- softmax: combine halves, *0.125, softmax 4096, write bf16 probs ----------------
__global__ __launch_bounds__(256) void softmax_kernel(const float* __restrict__ scp,
                                                      unsigned int* __restrict__ pb)
{
    int row = blockIdx.x;   // b*HH + h
    int t = threadIdx.x;
    const float4* p0 = reinterpret_cast<const float4*>(scp + (long)row * SS);
    const float4* p1 = reinterpret_cast<const float4*>(scp + ((long)BB * HH + row) * SS);
    float4 v[4];
    float mx = -3.0e38f;
    #pragma unroll
    for (int i = 0; i < 4; ++i) {
        float4 a = p0[t + 256 * i], c = p1[t + 256 * i];
        v[i] = make_float4((a.x + c.x) * 0.125f, (a.y + c.y) * 0.125f,
                           (a.z + c.z) * 0.125f, (a.w + c.w) * 0.125f);
        mx = fmaxf(mx, fmaxf(fmaxf(v[i].x, v[i].y), fmaxf(v[i].z, v[i].w)));
    }
    __shared__ float red[4];
    for (int off = 32; off; off >>= 1) mx = fmaxf(mx, __shfl_xor(mx, off, 64));
    if ((t & 63) == 0) red[t >> 6] = mx;
    __syncthreads();
    mx = fmaxf(fmaxf(red[0], red[1]), fmaxf(red[2], red[3]));
    __syncthreads();
    float sum = 0.f;
    #pragma unroll
    for (int i = 0; i < 4; ++i) {
        v[i].x = expf(v[i].x - mx); v[i].y = expf(v[i].y - mx);
        v[i].z = expf(v[i].z - mx); v[i].w = expf(v[i].w - mx);
        sum += v[i].x + v[i].y + v[i].z + v[i].w;
    }
    for (int off = 32; off; off >>= 1) sum += __shfl_xor(sum, off, 64);
    if ((t & 63) == 0) red[t >> 6] = sum;
    __syncthreads();
    sum = red[0] + red[1] + red[2] + red[3];
    float inv = 1.f / sum;
    #pragma unroll
    for (int i = 0; i < 4; ++i) {
        unsigned d0 = (unsigned)f2bf(v[i].x * inv) | ((unsigned)f2bf(v[i].y * inv) << 16);
        unsigned d1 = (unsigned)f2bf(v[i].z * inv) | ((unsigned)f2bf(v[i].w * inv) << 16);
        reinterpret_cast<uint2*>(pb)[(long)row * 1024 + t + 256 * i] = make_uint2(d0, d1);
    }
}

// ---------------- ctx partial: ctxp[sc][b][h][e] = sum_{s in chunk} P[b,h,s]*x[b,s,e]  (MFMA) ----------------
// grid (DD/64, NCS, BB), block 256 = 4 waves, wave owns 16 e. No LDS.
__global__ __launch_bounds__(256) void ctx_kernel(const float* __restrict__ tgt,
                                                  const float* __restrict__ pe,
                                                  const unsigned short* __restrict__ pb,
                                                  float* __restrict__ ctxp)
{
    int b = blockIdx.z, sc = blockIdx.y, et = blockIdx.x;
    int wave = threadIdx.x >> 6, lane = threadIdx.x & 63;
    int q = lane >> 4, n = lane & 15;
    int e = et * 64 + wave * 16 + n;
    f32x4 acc = {0.f, 0.f, 0.f, 0.f};
    const unsigned short* prow = pb + ((long)(b * HH) + n) * SS;
    #pragma unroll 2
    for (int ks = 0; ks < 16; ++ks) {
        int sb = sc * 512 + ks * 32 + q * 8;
        bf16x8 a = *reinterpret_cast<const bf16x8*>(prow + sb);   // A[m=h][k=s]
        union { short sh[8]; bf16x8 v; } bu;
        #pragma unroll
        for (int j = 0; j < 8; ++j) {
            float xv = tgt[((long)b * SS + sb + j) * DD + e] + pe[(long)(sb + j) * DD + e];
            bu.sh[j] = (short)f2bf(xv);
        }
        acc = __builtin_amdgcn_mfma_f32_16x16x32_bf16(a, bu.v, acc, 0, 0, 0);
    }
    #pragma unroll
    for (int r = 0; r < 4; ++r)
        ctxp[(((long)sc * BB + b) * HH + q * 4 + r) * DD + e] = acc[r];
}

// ---------------- reduce ctx partials over NCS chunks ----------------
__global__ __launch_bounds__(256) void ctxred_kernel(const float* __restrict__ ctxp,
                                                     float* __restrict__ ctx)
{
    long i = ((long)blockIdx.x * 256 + threadIdx.x) * 4;
    float4 s = make_float4(0.f, 0.f, 0.f, 0.f);
    #pragma unroll
    for (int c = 0; c < NCS; ++c) {
        float4 p = *reinterpret_cast<const float4*>(ctxp + (long)c * BB * HH * DD + i);
        s.x += p.x; s.y += p.y; s.z += p.z; s.w += p.w;
    }
    *reinterpret_cast<float4*>(ctx + i) = s;
}

// ---------------- o[b, j] = sum_e wv[j,e]*ctx[b, j>>6, e] + bv[j] ----------------
__global__ __launch_bounds__(256) void ov_kernel(const float* __restrict__ ctx,
                                                 const float* __restrict__ wv,
                                                 const float* __restrict__ bv,
                                                 float* __restrict__ o)
{
    int wave = threadIdx.x >> 6, lane = threadIdx.x & 63;
    int j = blockIdx.x * 4 + wave;
    if (j >= DD) return;
    int h = j >> 6;
    float acc[8] = {0.f,0.f,0.f,0.f,0.f,0.f,0.f,0.f};
    const float4* w4 = reinterpret_cast<const float4*>(wv + (long)j * DD);
    float4 wreg[4];
    #pragma unroll
    for (int kb = 0; kb < 4; ++kb) wreg[kb] = w4[kb * 64 + lane];
    #pragma unroll
    for (int kb = 0; kb < 4; ++kb) {
        int k4 = kb * 64 + lane;
        float4 w = wreg[kb];
        #pragma unroll
        for (int b = 0; b < 8; ++b) {
            float4 a = reinterpret_cast<const float4*>(ctx + ((long)(b * HH + h)) * DD)[k4];
            acc[b] += a.x * w.x + a.y * w.y + a.z * w.z + a.w * w.w;
        }
    }
    #pragma unroll
    for (int b = 0; b < 8; ++b)
        for (int off = 32; off; off >>= 1) acc[b] += __shfl_xor(acc[b], off, 64);
    if (lane == 0) {
        float bs = bv[j];
        #pragma unroll
        for (int b = 0; b < 8; ++b) o[(long)b * DD + j] = acc[b] + bs;
    }
}

extern "C" void kernel_launch(void* const* d_in, const int* in_sizes, int n_in,
                              void* d_out, int out_size, void* d_ws, size_t ws_size,
                              hipStream_t stream)
{
    const float* tgt        = (const float*)d_in[0];
    const float* in_proj_w  = (const float*)d_in[1];
    const float* in_proj_b  = (const float*)d_in[2];
    const float* out_proj_w = (const float*)d_in[3];
    const float* out_proj_b = (const float*)d_in[4];
    const float* ln1_w      = (const float*)d_in[5];
    const float* ln1_b      = (const float*)d_in[6];
    const float* lin1_w     = (const float*)d_in[7];
    const float* lin1_b     = (const float*)d_in[8];
    const float* lin2_w     = (const float*)d_in[9];
    const float* lin2_b     = (const float*)d_in[10];
    const float* ln2_w      = (const float*)d_in[11];
    const float* ln2_b      = (const float*)d_in[12];
    const float* w_out      = (const float*)d_in[13];
    const float* b_out      = (const float*)d_in[14];

    float* ws = (float*)d_ws;
    long off = 0;
    float* pe   = ws + off;  off += (long)SS * DD;              // 4.19M
    float* scp  = ws + off;  off += 2L * BB * HH * SS;          // 1.05M
    float* ctxp = ws + off;  off += (long)NCS * BB * HH * DD;   // 1.05M
    float* ctx  = ws + off;  off += (long)BB * HH * DD;         // 131K
    unsigned short* pb = (unsigned short*)(ws + off); off += (long)BB * HH * SS / 2;  // 1MB
    unsigned short* ub = (unsigned short*)(ws + off); off += (long)BB * HH * DD / 2;  // 256KB
    float* Q    = ws + off;  off += (long)BB * DD;
    float* o    = ws + off;  off += (long)BB * DD;
    float* vb   = ws + off;  off += (long)BB * DD;
    float* o2   = ws + off;  off += (long)BB * DD;
    float* hb   = ws + off;  off += (long)BB * FF;
    float* z    = ws + off;  off += (long)BB * DD;

    const float* tgt_last = tgt + (long)(SS - 1) * DD;
    const float* pe_last  = pe + (long)(SS - 1) * DD;

    // 1. positional encoding table
    pe_kernel<<<SS, 256, 0, stream>>>(pe);

    // 2. Q = (tgt_last + pe_last) @ wq0^T + bq0
    gemm8k<1024, 0, 0><<<DD / 4, 256, 0, stream>>>(
        tgt_last, (long)SS * DD, pe_last, 0L, in_proj_w, in_proj_b,
        nullptr, 0L, nullptr, 0L, nullptr, nullptr, nullptr, Q, DD);

    // 3. u (bf16) — bk dropped (softmax-invariant)
    u_kernel<<<dim3(4, 16), 256, 0, stream>>>(Q, in_proj_w + (long)DD * DD, ub);

    // 4. attention: MFMA score partials -> softmax(+bf16 probs) -> MFMA ctx partials -> reduce
    score_kernel<<<dim3(SS / 64, 2, BB), 256, 0, stream>>>(tgt, pe, ub, scp);
    softmax_kernel<<<BB * HH, 256, 0, stream>>>(scp, (unsigned int*)pb);
    ctx_kernel<<<dim3(DD / 64, NCS, BB), 256, 0, stream>>>(tgt, pe, pb, ctxp);
    ctxred_kernel<<<(BB * HH * DD) / 1024, 256, 0, stream>>>(ctxp, ctx);

    // 5. o = wv0 @ ctx + bv0
    ov_kernel<<<DD / 4, 256, 0, stream>>>(ctx, in_proj_w + 2L * DD * DD, in_proj_b + 2 * DD, o);

    // 6. layer-0 tail (ln folded into consumers)
    gemm8k<1024, 0, 0><<<DD / 4, 256, 0, stream>>>(
        o, (long)DD, nullptr, 0L, out_proj_w, out_proj_b,
        tgt_last, (long)SS * DD, pe_last, 0L, nullptr, nullptr, nullptr, o2, DD);
    gemm8k<1024, 1, 1><<<FF / 4, 256, 0, stream>>>(
        o2, (long)DD, nullptr, 0L, lin1_w, lin1_b,
        nullptr, 0L, nullptr, 0L, ln1_w, ln1_b, nullptr, hb, FF);
    gemm8k<2048, 0, 2><<<DD / 4, 256, 0, stream>>>(
        hb, (long)FF, nullptr, 0L, lin2_w, lin2_b,
        nullptr, 0L, nullptr, 0L, ln1_w, ln1_b, o2, z, DD);

    // 7. layers 1..5 (seq len 1 -> attn out = ln2(z) @ wv^T + bv)
    for (int i = 1; i < LL; ++i) {
        const float* wv_i  = in_proj_w + (long)i * 3 * DD * DD + 2L * DD * DD;
        const float* bv_i  = in_proj_b + (long)i * 3 * DD + 2 * DD;
        const float* l2w_p = ln2_w + (long)(i - 1) * DD;   // ln of layer i-1 output
        const float* l2b_p = ln2_b + (long)(i - 1) * DD;
        const float* l1w   = ln1_w + (long)i * DD;
        const float* l1b   = ln1_b + (long)i * DD;
        gemm8k<1024, 0, 1><<<DD / 4, 256, 0, stream>>>(
            z, (long)DD, nullptr, 0L, wv_i, bv_i,
            nullptr, 0L, nullptr, 0L, l2w_p, l2b_p, nullptr, vb, DD);
        gemm8k<1024, 0, 2><<<DD / 4, 256, 0, stream>>>(
            vb, (long)DD, nullptr, 0L,
            out_proj_w + (long)i * DD * DD, out_proj_b + (long)i * DD,
            nullptr, 0L, nullptr, 0L, l2w_p, l2b_p, z, o2, DD);
        gemm8k<1024, 1, 1><<<FF / 4, 256, 0, stream>>>(
            o2, (long)DD, nullptr, 0L,
            lin1_w + (long)i * FF * DD, lin1_b + (long)i * FF,
            nullptr, 0L, nullptr, 0L, l1w, l1b, nullptr, hb, FF);
        gemm8k<2048, 0, 2><<<DD / 4, 256, 0, stream>>>(
            hb, (long)FF, nullptr, 0L,
            lin2_w + (long)i * DD * FF, lin2_b + (long)i * DD,
            nullptr, 0L, nullptr, 0L, l1w, l1b, o2, z, DD);
    }

    // 8. final: out = ln2_5(z) @ w_out^T + b_out
    gemm8k<1024, 0, 1><<<VV / 4, 256, 0, stream>>>(
        z, (long)DD, nullptr, 0L, w_out, b_out,
        nullptr, 0L, nullptr, 0L,
        ln2_w + (long)(LL - 1) * DD, ln2_b + (long)(LL - 1) * DD, nullptr,
        (float*)d_out, VV);
}